// Round 16
// baseline (196.305 us; speedup 1.0000x reference)
//
#include <hip/hip_runtime.h>

// SnEncoder on MI355X, round 16 = round 15 (192.5us best) with k_h2red's inner
// loops register-staged in batches of 8 (proven serial-issue fix; identical sums).
// Everything else byte-identical to round 15. ws >= ~107MB.

typedef float f32x4 __attribute__((ext_vector_type(4)));
typedef __bf16 bfv8 __attribute__((ext_vector_type(8)));
typedef unsigned int u32x4v __attribute__((ext_vector_type(4)));
typedef unsigned short u16x8 __attribute__((ext_vector_type(8)));
typedef unsigned short u16x4 __attribute__((ext_vector_type(4)));

#define DEVI static __device__ __forceinline__

DEVI unsigned f2bfu(float f){
  unsigned u = __float_as_uint(f);
  return (u + 0x7fffu + ((u >> 16) & 1u)) >> 16;   // RNE f32->bf16 bits
}
DEVI float bf2f(unsigned short u){
  return __uint_as_float(((unsigned)u) << 16);
}
DEVI bfv8 ld_bf8(const unsigned short* p){
  u32x4v v = *reinterpret_cast<const u32x4v*>(p);
  return __builtin_bit_cast(bfv8, v);
}

// ---------------- workspace offsets (floats) ----------------
#define O_WP    0
#define O_WQ    1024
#define O_WR    2048
#define O_WAV   3072
#define O_WBU   4096
#define O_WBV   5120
#define O_WCU   6144
#define O_WD    7168
#define O_U     8192
#define O_V     16384
#define O_GM    24576
#define O_AB    24832
#define O_BB    57600
#define O_CB    90368
#define O_SUM1  123136
#define O_SSQ1  123200
#define O_SC1   123264
#define O_SH1   123328
#define O_SUM2  123392
#define O_SSQ2  123456
#define O_SUMC  123648
#define O_SSQC  123712
#define O_S123  123776
#define O_S23H  125824
#define O_S13H  158592
#define O_S12H  191360
#define O_A2    224128
#define O_B2    256896
#define O_C2    289664
#define O_T23   322432
#define O_T13   355200
#define O_T12   387968
#define O_OUT1  420736
#define O_P1    458752
#define O_P2T   458752
// P2T (bf16 [512][64][32] = 1M u16) reuses P1 (dead after sweep1)
#define O_Q1    1507328
#define O_R1    2555904
#define O_S1S   3604480
#define O_S2S   4653056
#define O_S3S   5701632
#define O_Q2    7798784
#define O_R2    8847360
#define O_H1    9895936
#define O_BN1P  26673152
#define O_W2BT  26683392
// total ~26,687,488 floats = ~106.8 MB

// ======= setup: means (0..15), wcomb (16..31), W2bfT (32), zero-accum (33,34) =======
__global__ __launch_bounds__(512) void k_setup(const float* __restrict__ x, const float* __restrict__ W1,
                                               const float* __restrict__ W2, float* __restrict__ ws){
  int blk = blockIdx.x; int t = threadIdx.x;
  __shared__ float ul[32][16];
  if (blk < 16){
    int b = blk; int r = t >> 4, c = t & 15;
    float au = 0.f, av = 0.f;
    for (int i = 0; i < 32; i++){
      au += x[((b*32+i)*32+r)*16+c];
      av += x[((b*32+r)*32+i)*16+c];
    }
    au *= (1.f/32.f); av *= (1.f/32.f);
    ws[O_U + (b*32+r)*16+c] = au;
    ws[O_V + (b*32+r)*16+c] = av;
    ul[r][c] = au;
    __syncthreads();
    if (t < 16){
      float g = 0.f;
      for (int r2 = 0; r2 < 32; r2++) g += ul[r2][t];
      ws[O_GM + b*16+t] = g * (1.f/32.f);
    }
  } else if (blk < 32){
    if (t < 64){
      int c = blk - 16; int d = t;
#define W1AT(tt,comp) W1[(((tt)*48 + (comp)*16 + c)*64) + d]
      ws[O_WP  + c*64+d] = W1AT(0,0) + W1AT(3,0);
      ws[O_WQ  + c*64+d] = W1AT(0,1) + W1AT(2,1);
      ws[O_WR  + c*64+d] = W1AT(0,2) + W1AT(1,2);
      ws[O_WAV + c*64+d] = W1AT(2,0) + W1AT(3,1) + W1AT(4,0) + W1AT(4,1);
      ws[O_WBU + c*64+d] = W1AT(1,0) + W1AT(5,0);
      ws[O_WBV + c*64+d] = W1AT(3,2) + W1AT(5,2);
      ws[O_WCU + c*64+d] = W1AT(1,1) + W1AT(2,2) + W1AT(6,1) + W1AT(6,2);
      ws[O_WD  + c*64+d] = W1AT(4,2) + W1AT(5,1) + W1AT(6,0) + W1AT(7,0) + W1AT(7,1) + W1AT(7,2);
#undef W1AT
    }
  } else if (blk == 32){
    unsigned short* W2bt = (unsigned short*)(ws + O_W2BT);
    for (int e = t; e < 4096; e += 512){
      int dcol = e >> 6, row = e & 63;
      W2bt[e] = (unsigned short)f2bfu(W2[row*64 + dcol]);
    }
  } else if (blk == 33){
    for (int e = t; e < 1664; e += 512) ws[O_SUM1 + e] = 0.f;
  } else {
    for (int e = t; e < 10240; e += 512) ws[O_BN1P + e] = 0.f;
  }
}

// ================= pairs1 (blk<1024: 16 bids each, weights in LDS) + singles (blk>=1024) =================
__global__ __launch_bounds__(64) void k_pairs1s(const float* __restrict__ x, const float* __restrict__ xn,
                                                const float* __restrict__ Wn1, float* __restrict__ ws){
  int blk = blockIdx.x; int t = threadIdx.x;
  if (blk < 1024){
    __shared__ float wl[3072];
    __shared__ float xl[256];
    for (int idx = t; idx < 1024; idx += 64){
      wl[idx]        = ws[O_WP + idx];
      wl[1024 + idx] = ws[O_WQ + idx];
      wl[2048 + idx] = ws[O_WR + idx];
    }
    for (int idx = t; idx < 256; idx += 64) xl[idx] = x[blk*256 + idx];
    __syncthreads();
    for (int bb = 0; bb < 16; bb++){
      int bid = blk*16 + bb;
      float aP = 0.f, aQ = 0.f, aR = 0.f;
      #pragma unroll
      for (int c = 0; c < 16; c++){
        float xv = xl[bb*16+c];
        aP += xv * wl[c*64 + t];
        aQ += xv * wl[1024 + c*64 + t];
        aR += xv * wl[2048 + c*64 + t];
      }
      int o = bid*64 + t;
      ws[O_P1 + o] = aP; ws[O_Q1 + o] = aQ; ws[O_R1 + o] = aR;
    }
  } else {
    __shared__ float uv[16], vv[16], gml[16], xnl[8];
    int bid = blk - 1024; int b = bid >> 5; int d = t;
    if (d < 16){ uv[d] = ws[O_U + bid*16+d]; vv[d] = ws[O_V + bid*16+d]; gml[d] = ws[O_GM + b*16+d]; }
    if (d < 8) xnl[d] = xn[bid*8 + d];
    __syncthreads();
    float A = 0.f, Bv = 0.f, Cv = 0.f;
    for (int c = 0; c < 16; c++){
      A  += vv[c]*ws[O_WAV + c*64+d] + gml[c]*ws[O_WD + c*64+d];
      Bv += uv[c]*ws[O_WBU + c*64+d] + vv[c]*ws[O_WBV + c*64+d];
      Cv += uv[c]*ws[O_WCU + c*64+d];
    }
    for (int c = 0; c < 8; c++){
      A  += xnl[c]*Wn1[(c)*64 + d];
      Bv += xnl[c]*Wn1[(8 + c)*64 + d];
      Cv += xnl[c]*Wn1[(16 + c)*64 + d];
    }
    ws[O_AB + bid*64+d] = A; ws[O_BB + bid*64+d] = Bv; ws[O_CB + bid*64+d] = Cv;
  }
}

// ================= BN1 closed-form stage 1: 10 per-b partials =================
__global__ __launch_bounds__(256) void k_bn1a(float* __restrict__ ws){
  int blk = blockIdx.x; int b = blk >> 3, ms = blk & 7;
  int t = threadIdx.x; int w = t >> 6, d = t & 63;
  int m = ms*4 + w;
  const float* P1 = ws + O_P1 + b*65536;
  const float* Q1 = ws + O_Q1 + b*65536;
  const float* R1 = ws + O_R1 + b*65536;
  float pR=0.f,pC=0.f,qR=0.f,qC=0.f,rR=0.f,rC=0.f,s2=0.f;
  for (int u = 0; u < 32; u++){
    float vp = P1[(m*32+u)*64+d];  pR += vp; s2 += vp*vp;
    float vq = Q1[(m*32+u)*64+d];  qR += vq; s2 += vq*vq;
    float vr = R1[(m*32+u)*64+d];  rR += vr; s2 += vr*vr;
    pC += P1[(u*32+m)*64+d];
    qC += Q1[(u*32+m)*64+d];
    rC += R1[(u*32+m)*64+d];
  }
  float a  = ws[O_AB + (b*32+m)*64+d];
  float bv = ws[O_BB + (b*32+m)*64+d];
  float cv = ws[O_CB + (b*32+m)*64+d];
  float sabc2 = a*a + bv*bv + cv*cv;
  float cidx = pR*qR + pC*rR + qC*rC;
  float cps  = pR*a + pC*bv + qR*a + qC*cv + rR*bv + rC*cv;
  __shared__ float red[10][4][64];
  red[0][w][d]=s2; red[1][w][d]=sabc2; red[2][w][d]=cidx; red[3][w][d]=cps;
  red[4][w][d]=pR; red[5][w][d]=qR; red[6][w][d]=rR;
  red[7][w][d]=a;  red[8][w][d]=bv;  red[9][w][d]=cv;
  __syncthreads();
  if (t < 64){
    #pragma unroll
    for (int q = 0; q < 10; q++){
      float v = red[q][0][t]+red[q][1][t]+red[q][2][t]+red[q][3][t];
      atomicAdd(&ws[O_BN1P + q*1024 + b*64 + t], v);
    }
  }
}

// ================= BN1 stage 2 + finalize (SC1/SH1) =================
__global__ __launch_bounds__(64) void k_bn1bfin(const float* __restrict__ g1, const float* __restrict__ b1,
                                                float* __restrict__ ws){
  int d = threadIdx.x;
  float SUM = 0.f, SSQ = 0.f;
  for (int b = 0; b < 16; b++){
    float s2   = ws[O_BN1P + 0*1024 + b*64+d];
    float sab2 = ws[O_BN1P + 1*1024 + b*64+d];
    float cidx = ws[O_BN1P + 2*1024 + b*64+d];
    float cps  = ws[O_BN1P + 3*1024 + b*64+d];
    float Sp   = ws[O_BN1P + 4*1024 + b*64+d];
    float Sq   = ws[O_BN1P + 5*1024 + b*64+d];
    float Sr   = ws[O_BN1P + 6*1024 + b*64+d];
    float Sa   = ws[O_BN1P + 7*1024 + b*64+d];
    float Sb   = ws[O_BN1P + 8*1024 + b*64+d];
    float Sc   = ws[O_BN1P + 9*1024 + b*64+d];
    SUM += 32.f*(Sp+Sq+Sr) + 1024.f*(Sa+Sb+Sc);
    SSQ += 32.f*s2 + 1024.f*sab2 + 2.f*cidx + 64.f*cps
         + 2.f*(Sp*Sc + Sq*Sb + Sr*Sa)
         + 64.f*(Sa*Sb + Sa*Sc + Sb*Sc);
  }
  float mu = SUM*(1.f/524288.f);
  float var = SSQ*(1.f/524288.f) - mu*mu;
  float sc = rsqrtf(var + 1e-5f) * g1[d];
  ws[O_SC1+d] = sc;
  ws[O_SH1+d] = b1[d] - mu*sc;
}

// ================= sweep: h1 -> bf16 H1, S2S, S3S  [R15 exact] =================
__global__ __launch_bounds__(256) void k_sweep1(float* __restrict__ ws, unsigned short* __restrict__ H1){
  int bid = blockIdx.x; int b = bid >> 5;
  int t = threadIdx.x;
  __shared__ float PB[2048], QC[2048];
  __shared__ float s2p[8192];
  for (int idx = t; idx < 2048; idx += 256){
    int q = idx >> 6, d = idx & 63;
    float sc = ws[O_SC1+d];
    PB[idx] = (ws[O_P1 + (bid*32+q)*64+d] + ws[O_BB + (b*32+q)*64+d] + ws[O_AB + bid*64+d]) * sc;
    QC[idx] = (ws[O_Q1 + (bid*32+q)*64+d] + ws[O_CB + (b*32+q)*64+d]) * sc + ws[O_SH1+d];
  }
  __syncthreads();
  int w = t >> 6, d = t & 63;
  float scd = ws[O_SC1+d];
  float acc2[32];
  #pragma unroll
  for (int k = 0; k < 32; k++) acc2[k] = 0.f;
  for (int jj = 0; jj < 8; jj++){
    int j = w*8 + jj;
    float pb = PB[j*64+d];
    const float* r1row = ws + O_R1 + ((b*32+j)*32)*64 + d;
    unsigned short* hrow = H1 + (((size_t)bid*32+j)*32)*64 + d;
    float r1s[32];
    #pragma unroll
    for (int k = 0; k < 32; k++) r1s[k] = r1row[k*64];
    float a3 = 0.f;
    #pragma unroll
    for (int k = 0; k < 32; k++){
      float h = fmaxf(fmaf(r1s[k], scd, pb + QC[k*64+d]), 0.f);
      a3 += h; acc2[k] += h;
      hrow[k*64] = (unsigned short)f2bfu(h);
    }
    ws[O_S3S + (bid*32+j)*64+d] = a3;
  }
  #pragma unroll
  for (int k = 0; k < 32; k++) s2p[(w*32+k)*64+d] = acc2[k];
  __syncthreads();
  for (int idx = t; idx < 2048; idx += 256){
    int k = idx >> 6, dd = idx & 63;
    ws[O_S2S + (bid*32+k)*64+dd] = s2p[k*64+dd] + s2p[2048+k*64+dd] + s2p[4096+k*64+dd] + s2p[6144+k*64+dd];
  }
}

// ================= S1S = sum_i h1 (register-staged loads); then P2T, Q2, R2 =================
__global__ __launch_bounds__(512) void k_hredp2(const float* __restrict__ W2, float* __restrict__ ws,
                                                const unsigned short* __restrict__ H1,
                                                unsigned short* __restrict__ P2T){
  int bid = blockIdx.x; int b = bid >> 5, j = bid & 31;
  int t = threadIdx.x;
  __shared__ float s1[2048], s1b[2048], s2[2048], s3[2048];
  int tt = t & 255, half = t >> 8;
  u32x4v vb[16];
  #pragma unroll
  for (int ii = 0; ii < 16; ii++){
    int i = half*16 + ii;
    vb[ii] = *reinterpret_cast<const u32x4v*>(H1 + (((size_t)(b*32+i)*32+j)*32)*64 + tt*8);
  }
  float acc[8];
  #pragma unroll
  for (int e = 0; e < 8; e++) acc[e] = 0.f;
  #pragma unroll
  for (int ii = 0; ii < 16; ii++){
    u16x8 v = __builtin_bit_cast(u16x8, vb[ii]);
    #pragma unroll
    for (int e = 0; e < 8; e++) acc[e] += bf2f(v[e]);
  }
  float* dsth = half ? s1b : s1;
  #pragma unroll
  for (int e = 0; e < 8; e++) dsth[tt*8+e] = acc[e];
  {
    int idx = t;
    *(f32x4*)&s2[idx*4] = *(const f32x4*)&ws[O_S2S + bid*2048 + idx*4];
    *(f32x4*)&s3[idx*4] = *(const f32x4*)&ws[O_S3S + bid*2048 + idx*4];
  }
  __syncthreads();
  for (int idx = t; idx < 2048; idx += 512){
    float v = s1[idx] + s1b[idx];
    s1[idx] = v;
    ws[O_S1S + (size_t)bid*2048 + idx] = v;
  }
  __syncthreads();
  int d = t & 63; int g = t >> 6;
  float pv[4] = {0,0,0,0}, qv[4] = {0,0,0,0}, rv[4] = {0,0,0,0};
  for (int c = 0; c < 64; c++){
    float wp = W2[(64 +c)*64 + d];
    float wq = W2[(128+c)*64 + d];
    float wr = W2[(192+c)*64 + d];
    #pragma unroll
    for (int rr = 0; rr < 4; rr++){
      int row = g*4 + rr;
      pv[rr] = fmaf(s1[row*64+c], wp, pv[rr]);
      qv[rr] = fmaf(s2[row*64+c], wq, qv[rr]);
      rv[rr] = fmaf(s3[row*64+c], wr, rv[rr]);
    }
  }
  #pragma unroll
  for (int rr = 0; rr < 4; rr++){
    int row = g*4 + rr;   // k index
    P2T[(size_t)bid*2048 + d*32 + row] = (unsigned short)f2bfu(pv[rr] * (1.f/32.f));
    ws[O_Q2 + (bid*32+row)*64 + d] = qv[rr] * (1.f/32.f);
    ws[O_R2 + (bid*32+row)*64 + d] = rv[rr] * (1.f/32.f);
  }
}

// ================= order-1 means of h1 (+ S123 accumulation) =================
__global__ __launch_bounds__(64) void k_sred(float* __restrict__ ws){
  int bid = blockIdx.x; int b = bid >> 5, m = bid & 31; int d = threadIdx.x;
  float s23 = 0.f, s13 = 0.f, s12 = 0.f;
  for (int k = 0; k < 32; k++){
    s23 += ws[O_S2S + (bid*32+k)*64+d];
    s13 += ws[O_S1S + (bid*32+k)*64+d];
  }
  for (int j = 0; j < 32; j++) s12 += ws[O_S1S + ((b*32+j)*32+m)*64+d];
  ws[O_S23H + bid*64+d] = s23 * (1.f/1024.f);
  ws[O_S13H + bid*64+d] = s13 * (1.f/1024.f);
  ws[O_S12H + bid*64+d] = s12 * (1.f/1024.f);
  atomicAdd(&ws[O_S123 + b*64+d], s23 * (1.f/32768.f));
}

// ================= A2/B2/C2 (D2 inline from S123) =================
__global__ __launch_bounds__(64) void k_ss2(const float* __restrict__ W2, float* __restrict__ ws){
  int bid = blockIdx.x; int b = bid >> 5; int t = threadIdx.x;
  __shared__ float r23[64], r13[64], r12[64], s123l[64];
  r23[t] = ws[O_S23H + bid*64+t];
  r13[t] = ws[O_S13H + bid*64+t];
  r12[t] = ws[O_S12H + bid*64+t];
  s123l[t] = ws[O_S123 + b*64+t];
  __syncthreads();
  float a = 0.f, bv = 0.f, cv = 0.f;
  for (int c = 0; c < 64; c++){
    a  += r23[c] * W2[(256 + c)*64 + t] + s123l[c] * W2[(448 + c)*64 + t];
    bv += r13[c] * W2[(320 + c)*64 + t];
    cv += r12[c] * W2[(384 + c)*64 + t];
  }
  ws[O_A2 + bid*64+t] = a; ws[O_B2 + bid*64+t] = bv; ws[O_C2 + bid*64+t] = cv;
}

// ================= heavy pass: y2 f32 -> BN2 partials + bf16 store in place [R12 exact] =================
__global__ __launch_bounds__(256) void k_g(float* __restrict__ ws, unsigned short* __restrict__ H1,
                                           const unsigned short* __restrict__ P2T){
  int blk = blockIdx.x;
  int bid = blk >> 2; int b = bid >> 5; int jh = blk & 3;
  int t = threadIdx.x; int w = t >> 6, lane = t & 63;
  int mt = w & 1, jp = w >> 1;
  int d15 = lane & 15, kq = lane >> 4;
  __shared__ float RB2s[512];
  __shared__ float redA[256], redB[256];
  for (int idx = t; idx < 512; idx += 256){
    int jj = idx >> 6, dd = idx & 63; int j = jh*8 + jj;
    RB2s[idx] = ws[O_R2 + (bid*32+j)*64+dd] + ws[O_B2 + (b*32+j)*64+dd] + ws[O_A2 + bid*64+dd];
  }
  const unsigned short* W2bt = (const unsigned short*)(ws + O_W2BT);
  bfv8 bw[4][2];
  #pragma unroll
  for (int nt = 0; nt < 4; nt++){
    #pragma unroll
    for (int ks = 0; ks < 2; ks++){
      bw[nt][ks] = ld_bf8(W2bt + (nt*16 + d15)*64 + ks*32 + kq*8);
    }
  }
  float qc2r[4][4];
  #pragma unroll
  for (int nt = 0; nt < 4; nt++){
    int dcol = nt*16 + d15;
    #pragma unroll
    for (int r = 0; r < 4; r++){
      int kl = mt*16 + kq*4 + r;
      qc2r[nt][r] = ws[O_Q2 + (bid*32+kl)*64 + dcol] + ws[O_C2 + (b*32+kl)*64 + dcol];
    }
  }
  float ssumv[4] = {0.f,0.f,0.f,0.f}, ssqv[4] = {0.f,0.f,0.f,0.f};
  __syncthreads();
  int aoff = (mt*16 + d15)*64 + kq*8;
  unsigned short* hbase = H1 + (size_t)bid*65536 + (size_t)jh*16384;
  bfv8 a0 = ld_bf8(hbase + jp*2048 + aoff);
  bfv8 a1 = ld_bf8(hbase + jp*2048 + aoff + 32);
  u16x4 p2cur[4];
  {
    const unsigned short* pb0 = P2T + (size_t)(b*32 + jh*8 + jp)*2048 + mt*16 + kq*4;
    #pragma unroll
    for (int nt = 0; nt < 4; nt++)
      p2cur[nt] = *reinterpret_cast<const u16x4*>(pb0 + (nt*16 + d15)*32);
  }
  #pragma unroll
  for (int s = 0; s < 4; s++){
    int jj = jp + 2*s;
    bfv8 n0 = a0, n1 = a1;
    u16x4 p2nxt[4];
    if (s < 3){
      n0 = ld_bf8(hbase + (jj+2)*2048 + aoff);
      n1 = ld_bf8(hbase + (jj+2)*2048 + aoff + 32);
      const unsigned short* pbn = P2T + (size_t)(b*32 + jh*8 + jj + 2)*2048 + mt*16 + kq*4;
      #pragma unroll
      for (int nt = 0; nt < 4; nt++)
        p2nxt[nt] = *reinterpret_cast<const u16x4*>(pbn + (nt*16 + d15)*32);
    }
    #pragma unroll
    for (int nt = 0; nt < 4; nt++){
      f32x4 acc = {0.f,0.f,0.f,0.f};
      acc = __builtin_amdgcn_mfma_f32_16x16x32_bf16(a0, bw[nt][0], acc, 0, 0, 0);
      acc = __builtin_amdgcn_mfma_f32_16x16x32_bf16(a1, bw[nt][1], acc, 0, 0, 0);
      int dcol = nt*16 + d15;
      float rb = RB2s[jj*64 + dcol];
      #pragma unroll
      for (int r = 0; r < 4; r++){
        int kl = mt*16 + kq*4 + r;   // C/D: col=lane&15, row=kq*4+r
        float val = acc[r] + rb + qc2r[nt][r] + bf2f(p2cur[nt][r]);
        ssumv[nt] += val; ssqv[nt] = fmaf(val, val, ssqv[nt]);
        hbase[jj*2048 + kl*64 + dcol] = (unsigned short)f2bfu(val);
      }
    }
    a0 = n0; a1 = n1;
    if (s < 3){
      #pragma unroll
      for (int nt = 0; nt < 4; nt++) p2cur[nt] = p2nxt[nt];
    }
  }
  #pragma unroll
  for (int nt = 0; nt < 4; nt++){
    float v = ssumv[nt]; v += __shfl_xor(v,16); v += __shfl_xor(v,32);
    float q = ssqv[nt];  q += __shfl_xor(q,16); q += __shfl_xor(q,32);
    if (lane < 16){ redA[(w*4+nt)*16 + lane] = v; redB[(w*4+nt)*16 + lane] = q; }
  }
  __syncthreads();
  if (t < 128){
    int half = t >> 6, ch = t & 63;
    int nt = ch >> 4, dd15 = ch & 15;
    const float* red = half ? redB : redA;
    float acc = 0.f;
    #pragma unroll
    for (int w2 = 0; w2 < 4; w2++) acc += red[(w2*4+nt)*16 + dd15];
    ws[O_S1S + (size_t)blk*128 + t] = acc;   // coalesced 512B per-block partial
  }
}

// ================= merge BN2 partials -> SUM2/SSQ2 =================
__global__ __launch_bounds__(128) void k_bn2red(float* __restrict__ ws){
  int p = blockIdx.x; int t = threadIdx.x;
  const float* base = ws + O_S1S + (size_t)p*256*128 + t;
  float a0=0.f,a1=0.f,a2=0.f,a3=0.f;
  for (int i = 0; i < 256; i += 4){
    a0 += base[(i+0)*128]; a1 += base[(i+1)*128];
    a2 += base[(i+2)*128]; a3 += base[(i+3)*128];
  }
  atomicAdd(&ws[O_SUM2 + t], (a0+a1)+(a2+a3));   // SUM2(0..63) | SSQ2(64..127) contiguous
}

// ================= stream y2-bf16 twice: batch-staged register reductions =================
__global__ __launch_bounds__(256) void k_h2red(const float* __restrict__ g2, const float* __restrict__ b2,
                                               float* __restrict__ ws, const unsigned short* __restrict__ Y2){
  int blk = blockIdx.x; int phase = blk >> 9; int bid = blk & 511;
  int t = threadIdx.x; int row = t >> 3, g = t & 7, d0 = g*8;
  float sc[8], sh[8];
  #pragma unroll
  for (int e = 0; e < 8; e++){
    int d = d0+e;
    float mu = ws[O_SUM2+d]*(1.f/524288.f);
    float var = ws[O_SSQ2+d]*(1.f/524288.f) - mu*mu;
    float s = rsqrtf(var + 1e-5f) * g2[d];
    sc[e] = s; sh[e] = b2[d] - mu*s;
  }
  float acc[8] = {0,0,0,0,0,0,0,0};
  const unsigned short* base = Y2 + (size_t)bid*65536;
  int stride = (phase == 0) ? 2048 : 64;
  const unsigned short* p = base + (phase == 0 ? row*64 : row*2048) + d0;
  for (int batch = 0; batch < 4; batch++){
    u32x4v vb[8];
    #pragma unroll
    for (int u = 0; u < 8; u++)
      vb[u] = *reinterpret_cast<const u32x4v*>(p + (batch*8 + u)*stride);
    #pragma unroll
    for (int u = 0; u < 8; u++){
      u16x8 v = __builtin_bit_cast(u16x8, vb[u]);
      #pragma unroll
      for (int e = 0; e < 8; e++) acc[e] += fmaxf(fmaf(bf2f(v[e]), sc[e], sh[e]), 0.f);
    }
  }
  float* o = ws + ((phase == 0) ? O_S2S : O_S3S) + (size_t)(bid*32+row)*64 + d0;
  *(f32x4*)o = *(f32x4*)&acc[0]; *(f32x4*)(o+4) = *(f32x4*)&acc[4];
}

// ================= fold partials: T12 = sum_i P12, T13 = sum_i P13, T23 = sum_k P12 =================
__global__ __launch_bounds__(64) void k_tred(float* __restrict__ ws){
  int bid = blockIdx.x; int b = bid >> 5, m = bid & 31; int d = threadIdx.x;
  float t12 = 0.f, t13 = 0.f, t23 = 0.f;
  for (int u = 0; u < 32; u++){
    t12 += ws[O_S2S + ((b*32+u)*32+m)*64 + d];
    t13 += ws[O_S3S + ((b*32+u)*32+m)*64 + d];
    t23 += ws[O_S2S + ((b*32+m)*32+u)*64 + d];
  }
  ws[O_T12 + bid*64+d] = t12;
  ws[O_T13 + bid*64+d] = t13;
  ws[O_T23 + bid*64+d] = t23;
}

// ================= final head (D3 inline) =================
__global__ __launch_bounds__(64) void k_final_out1(const float* __restrict__ Wc, float* __restrict__ ws){
  int bid = blockIdx.x; int b = bid >> 5; int t = threadIdx.x;
  __shared__ float r23[64], r13[64], r12[64], l[64];
  float a = 0.f;
  for (int m = 0; m < 32; m++) a += ws[O_T23 + (b*32+m)*64 + t];
  l[t] = a * (1.f/32768.f);
  r23[t] = ws[O_T23 + bid*64+t] * (1.f/1024.f);
  r13[t] = ws[O_T13 + bid*64+t] * (1.f/1024.f);
  r12[t] = ws[O_T12 + bid*64+t] * (1.f/1024.f);
  __syncthreads();
  float o = 0.f;
  for (int c = 0; c < 64; c++){
    o += r23[c]*Wc[c*64+t] + r13[c]*Wc[(64+c)*64+t] + r12[c]*Wc[(128+c)*64+t] + l[c]*Wc[(192+c)*64+t];
  }
  ws[O_OUT1 + bid*64+t] = o;
  atomicAdd(&ws[O_SUMC + t], o);
  atomicAdd(&ws[O_SSQC + t], o*o);
}

__global__ __launch_bounds__(64) void k_final_bn(const float* __restrict__ gc, const float* __restrict__ bc,
                                                 const float* __restrict__ ws, float* __restrict__ out){
  int bid = blockIdx.x; int t = threadIdx.x;
  float mu = ws[O_SUMC+t] * (1.f/512.f);
  float var = ws[O_SSQC+t] * (1.f/512.f) - mu*mu;
  float rs = rsqrtf(var + 1e-5f);
  out[bid*64 + t] = (ws[O_OUT1 + bid*64+t] - mu) * rs * gc[t] + bc[t];
}

extern "C" void kernel_launch(void* const* d_in, const int* in_sizes, int n_in,
                              void* d_out, int out_size, void* d_ws, size_t ws_size,
                              hipStream_t stream) {
  const float* x   = (const float*)d_in[0];
  const float* xn  = (const float*)d_in[1];
  const float* W1  = (const float*)d_in[2];
  const float* Wn1 = (const float*)d_in[3];
  const float* g1  = (const float*)d_in[4];
  const float* b1  = (const float*)d_in[5];
  const float* W2  = (const float*)d_in[6];
  const float* g2  = (const float*)d_in[7];
  const float* b2p = (const float*)d_in[8];
  const float* Wc  = (const float*)d_in[9];
  const float* gc  = (const float*)d_in[10];
  const float* bc  = (const float*)d_in[11];
  float* out = (float*)d_out;
  float* ws  = (float*)d_ws;
  unsigned short* H1  = (unsigned short*)(ws + O_H1);
  unsigned short* P2T = (unsigned short*)(ws + O_P2T);
  (void)in_sizes; (void)n_in; (void)out_size; (void)ws_size;

  k_setup   <<<35,    512, 0, stream>>>(x, W1, W2, ws);   // + zero-accum blocks
  k_pairs1s <<<1536,  64,  0, stream>>>(x, xn, Wn1, ws);
  k_bn1a    <<<128,   256, 0, stream>>>(ws);
  k_bn1bfin <<<1,     64,  0, stream>>>(g1, b1, ws);
  k_sweep1  <<<512,   256, 0, stream>>>(ws, H1);
  k_hredp2  <<<512,   512, 0, stream>>>(W2, ws, H1, P2T);
  k_sred    <<<512,   64,  0, stream>>>(ws);
  k_ss2     <<<512,   64,  0, stream>>>(W2, ws);
  k_g       <<<2048,  256, 0, stream>>>(ws, H1, P2T);   // y2 + bf16 in-place + BN2 partials
  k_bn2red  <<<8,     128, 0, stream>>>(ws);
  k_h2red   <<<1024,  256, 0, stream>>>(g2, b2p, ws, H1);
  k_tred    <<<512,   64,  0, stream>>>(ws);
  k_final_out1<<<512, 64,  0, stream>>>(Wc, ws);
  k_final_bn<<<512,   64,  0, stream>>>(gc, bc, ws, out);
}

// Round 17
// 191.097 us; speedup vs baseline: 1.0273x; 1.0273x over previous
//
#include <hip/hip_runtime.h>

// SnEncoder on MI355X, round 17 = round 15 EXACT (measured best, 192.5us).
// R16's h2red batch-staging was neutral/negative (streams don't benefit from
// the gather-staging fix) — reverted. ws >= ~107MB.

typedef float f32x4 __attribute__((ext_vector_type(4)));
typedef __bf16 bfv8 __attribute__((ext_vector_type(8)));
typedef unsigned int u32x4v __attribute__((ext_vector_type(4)));
typedef unsigned short u16x8 __attribute__((ext_vector_type(8)));
typedef unsigned short u16x4 __attribute__((ext_vector_type(4)));

#define DEVI static __device__ __forceinline__

DEVI unsigned f2bfu(float f){
  unsigned u = __float_as_uint(f);
  return (u + 0x7fffu + ((u >> 16) & 1u)) >> 16;   // RNE f32->bf16 bits
}
DEVI float bf2f(unsigned short u){
  return __uint_as_float(((unsigned)u) << 16);
}
DEVI bfv8 ld_bf8(const unsigned short* p){
  u32x4v v = *reinterpret_cast<const u32x4v*>(p);
  return __builtin_bit_cast(bfv8, v);
}

// ---------------- workspace offsets (floats) ----------------
#define O_WP    0
#define O_WQ    1024
#define O_WR    2048
#define O_WAV   3072
#define O_WBU   4096
#define O_WBV   5120
#define O_WCU   6144
#define O_WD    7168
#define O_U     8192
#define O_V     16384
#define O_GM    24576
#define O_AB    24832
#define O_BB    57600
#define O_CB    90368
#define O_SUM1  123136
#define O_SSQ1  123200
#define O_SC1   123264
#define O_SH1   123328
#define O_SUM2  123392
#define O_SSQ2  123456
#define O_SUMC  123648
#define O_SSQC  123712
#define O_S123  123776
#define O_S23H  125824
#define O_S13H  158592
#define O_S12H  191360
#define O_A2    224128
#define O_B2    256896
#define O_C2    289664
#define O_T23   322432
#define O_T13   355200
#define O_T12   387968
#define O_OUT1  420736
#define O_P1    458752
#define O_P2T   458752
// P2T (bf16 [512][64][32] = 1M u16) reuses P1 (dead after sweep1)
#define O_Q1    1507328
#define O_R1    2555904
#define O_S1S   3604480
#define O_S2S   4653056
#define O_S3S   5701632
#define O_Q2    7798784
#define O_R2    8847360
#define O_H1    9895936
#define O_BN1P  26673152
#define O_W2BT  26683392
// total ~26,687,488 floats = ~106.8 MB

// ======= setup: means (0..15), wcomb (16..31), W2bfT (32), zero-accum (33,34) =======
__global__ __launch_bounds__(512) void k_setup(const float* __restrict__ x, const float* __restrict__ W1,
                                               const float* __restrict__ W2, float* __restrict__ ws){
  int blk = blockIdx.x; int t = threadIdx.x;
  __shared__ float ul[32][16];
  if (blk < 16){
    int b = blk; int r = t >> 4, c = t & 15;
    float au = 0.f, av = 0.f;
    for (int i = 0; i < 32; i++){
      au += x[((b*32+i)*32+r)*16+c];
      av += x[((b*32+r)*32+i)*16+c];
    }
    au *= (1.f/32.f); av *= (1.f/32.f);
    ws[O_U + (b*32+r)*16+c] = au;
    ws[O_V + (b*32+r)*16+c] = av;
    ul[r][c] = au;
    __syncthreads();
    if (t < 16){
      float g = 0.f;
      for (int r2 = 0; r2 < 32; r2++) g += ul[r2][t];
      ws[O_GM + b*16+t] = g * (1.f/32.f);
    }
  } else if (blk < 32){
    if (t < 64){
      int c = blk - 16; int d = t;
#define W1AT(tt,comp) W1[(((tt)*48 + (comp)*16 + c)*64) + d]
      ws[O_WP  + c*64+d] = W1AT(0,0) + W1AT(3,0);
      ws[O_WQ  + c*64+d] = W1AT(0,1) + W1AT(2,1);
      ws[O_WR  + c*64+d] = W1AT(0,2) + W1AT(1,2);
      ws[O_WAV + c*64+d] = W1AT(2,0) + W1AT(3,1) + W1AT(4,0) + W1AT(4,1);
      ws[O_WBU + c*64+d] = W1AT(1,0) + W1AT(5,0);
      ws[O_WBV + c*64+d] = W1AT(3,2) + W1AT(5,2);
      ws[O_WCU + c*64+d] = W1AT(1,1) + W1AT(2,2) + W1AT(6,1) + W1AT(6,2);
      ws[O_WD  + c*64+d] = W1AT(4,2) + W1AT(5,1) + W1AT(6,0) + W1AT(7,0) + W1AT(7,1) + W1AT(7,2);
#undef W1AT
    }
  } else if (blk == 32){
    unsigned short* W2bt = (unsigned short*)(ws + O_W2BT);
    for (int e = t; e < 4096; e += 512){
      int dcol = e >> 6, row = e & 63;
      W2bt[e] = (unsigned short)f2bfu(W2[row*64 + dcol]);
    }
  } else if (blk == 33){
    for (int e = t; e < 1664; e += 512) ws[O_SUM1 + e] = 0.f;
  } else {
    for (int e = t; e < 10240; e += 512) ws[O_BN1P + e] = 0.f;
  }
}

// ================= pairs1 (blk<1024: 16 bids each, weights in LDS) + singles (blk>=1024) =================
__global__ __launch_bounds__(64) void k_pairs1s(const float* __restrict__ x, const float* __restrict__ xn,
                                                const float* __restrict__ Wn1, float* __restrict__ ws){
  int blk = blockIdx.x; int t = threadIdx.x;
  if (blk < 1024){
    __shared__ float wl[3072];
    __shared__ float xl[256];
    for (int idx = t; idx < 1024; idx += 64){
      wl[idx]        = ws[O_WP + idx];
      wl[1024 + idx] = ws[O_WQ + idx];
      wl[2048 + idx] = ws[O_WR + idx];
    }
    for (int idx = t; idx < 256; idx += 64) xl[idx] = x[blk*256 + idx];
    __syncthreads();
    for (int bb = 0; bb < 16; bb++){
      int bid = blk*16 + bb;
      float aP = 0.f, aQ = 0.f, aR = 0.f;
      #pragma unroll
      for (int c = 0; c < 16; c++){
        float xv = xl[bb*16+c];
        aP += xv * wl[c*64 + t];
        aQ += xv * wl[1024 + c*64 + t];
        aR += xv * wl[2048 + c*64 + t];
      }
      int o = bid*64 + t;
      ws[O_P1 + o] = aP; ws[O_Q1 + o] = aQ; ws[O_R1 + o] = aR;
    }
  } else {
    __shared__ float uv[16], vv[16], gml[16], xnl[8];
    int bid = blk - 1024; int b = bid >> 5; int d = t;
    if (d < 16){ uv[d] = ws[O_U + bid*16+d]; vv[d] = ws[O_V + bid*16+d]; gml[d] = ws[O_GM + b*16+d]; }
    if (d < 8) xnl[d] = xn[bid*8 + d];
    __syncthreads();
    float A = 0.f, Bv = 0.f, Cv = 0.f;
    for (int c = 0; c < 16; c++){
      A  += vv[c]*ws[O_WAV + c*64+d] + gml[c]*ws[O_WD + c*64+d];
      Bv += uv[c]*ws[O_WBU + c*64+d] + vv[c]*ws[O_WBV + c*64+d];
      Cv += uv[c]*ws[O_WCU + c*64+d];
    }
    for (int c = 0; c < 8; c++){
      A  += xnl[c]*Wn1[(c)*64 + d];
      Bv += xnl[c]*Wn1[(8 + c)*64 + d];
      Cv += xnl[c]*Wn1[(16 + c)*64 + d];
    }
    ws[O_AB + bid*64+d] = A; ws[O_BB + bid*64+d] = Bv; ws[O_CB + bid*64+d] = Cv;
  }
}

// ================= BN1 closed-form stage 1: 10 per-b partials =================
__global__ __launch_bounds__(256) void k_bn1a(float* __restrict__ ws){
  int blk = blockIdx.x; int b = blk >> 3, ms = blk & 7;
  int t = threadIdx.x; int w = t >> 6, d = t & 63;
  int m = ms*4 + w;
  const float* P1 = ws + O_P1 + b*65536;
  const float* Q1 = ws + O_Q1 + b*65536;
  const float* R1 = ws + O_R1 + b*65536;
  float pR=0.f,pC=0.f,qR=0.f,qC=0.f,rR=0.f,rC=0.f,s2=0.f;
  for (int u = 0; u < 32; u++){
    float vp = P1[(m*32+u)*64+d];  pR += vp; s2 += vp*vp;
    float vq = Q1[(m*32+u)*64+d];  qR += vq; s2 += vq*vq;
    float vr = R1[(m*32+u)*64+d];  rR += vr; s2 += vr*vr;
    pC += P1[(u*32+m)*64+d];
    qC += Q1[(u*32+m)*64+d];
    rC += R1[(u*32+m)*64+d];
  }
  float a  = ws[O_AB + (b*32+m)*64+d];
  float bv = ws[O_BB + (b*32+m)*64+d];
  float cv = ws[O_CB + (b*32+m)*64+d];
  float sabc2 = a*a + bv*bv + cv*cv;
  float cidx = pR*qR + pC*rR + qC*rC;
  float cps  = pR*a + pC*bv + qR*a + qC*cv + rR*bv + rC*cv;
  __shared__ float red[10][4][64];
  red[0][w][d]=s2; red[1][w][d]=sabc2; red[2][w][d]=cidx; red[3][w][d]=cps;
  red[4][w][d]=pR; red[5][w][d]=qR; red[6][w][d]=rR;
  red[7][w][d]=a;  red[8][w][d]=bv;  red[9][w][d]=cv;
  __syncthreads();
  if (t < 64){
    #pragma unroll
    for (int q = 0; q < 10; q++){
      float v = red[q][0][t]+red[q][1][t]+red[q][2][t]+red[q][3][t];
      atomicAdd(&ws[O_BN1P + q*1024 + b*64 + t], v);
    }
  }
}

// ================= BN1 stage 2 + finalize (SC1/SH1) =================
__global__ __launch_bounds__(64) void k_bn1bfin(const float* __restrict__ g1, const float* __restrict__ b1,
                                                float* __restrict__ ws){
  int d = threadIdx.x;
  float SUM = 0.f, SSQ = 0.f;
  for (int b = 0; b < 16; b++){
    float s2   = ws[O_BN1P + 0*1024 + b*64+d];
    float sab2 = ws[O_BN1P + 1*1024 + b*64+d];
    float cidx = ws[O_BN1P + 2*1024 + b*64+d];
    float cps  = ws[O_BN1P + 3*1024 + b*64+d];
    float Sp   = ws[O_BN1P + 4*1024 + b*64+d];
    float Sq   = ws[O_BN1P + 5*1024 + b*64+d];
    float Sr   = ws[O_BN1P + 6*1024 + b*64+d];
    float Sa   = ws[O_BN1P + 7*1024 + b*64+d];
    float Sb   = ws[O_BN1P + 8*1024 + b*64+d];
    float Sc   = ws[O_BN1P + 9*1024 + b*64+d];
    SUM += 32.f*(Sp+Sq+Sr) + 1024.f*(Sa+Sb+Sc);
    SSQ += 32.f*s2 + 1024.f*sab2 + 2.f*cidx + 64.f*cps
         + 2.f*(Sp*Sc + Sq*Sb + Sr*Sa)
         + 64.f*(Sa*Sb + Sa*Sc + Sb*Sc);
  }
  float mu = SUM*(1.f/524288.f);
  float var = SSQ*(1.f/524288.f) - mu*mu;
  float sc = rsqrtf(var + 1e-5f) * g1[d];
  ws[O_SC1+d] = sc;
  ws[O_SH1+d] = b1[d] - mu*sc;
}

// ================= sweep: h1 -> bf16 H1, S2S, S3S  [R1 register staging] =================
__global__ __launch_bounds__(256) void k_sweep1(float* __restrict__ ws, unsigned short* __restrict__ H1){
  int bid = blockIdx.x; int b = bid >> 5;
  int t = threadIdx.x;
  __shared__ float PB[2048], QC[2048];
  __shared__ float s2p[8192];
  for (int idx = t; idx < 2048; idx += 256){
    int q = idx >> 6, d = idx & 63;
    float sc = ws[O_SC1+d];
    PB[idx] = (ws[O_P1 + (bid*32+q)*64+d] + ws[O_BB + (b*32+q)*64+d] + ws[O_AB + bid*64+d]) * sc;
    QC[idx] = (ws[O_Q1 + (bid*32+q)*64+d] + ws[O_CB + (b*32+q)*64+d]) * sc + ws[O_SH1+d];
  }
  __syncthreads();
  int w = t >> 6, d = t & 63;
  float scd = ws[O_SC1+d];
  float acc2[32];
  #pragma unroll
  for (int k = 0; k < 32; k++) acc2[k] = 0.f;
  for (int jj = 0; jj < 8; jj++){
    int j = w*8 + jj;
    float pb = PB[j*64+d];
    const float* r1row = ws + O_R1 + ((b*32+j)*32)*64 + d;
    unsigned short* hrow = H1 + (((size_t)bid*32+j)*32)*64 + d;
    float r1s[32];
    #pragma unroll
    for (int k = 0; k < 32; k++) r1s[k] = r1row[k*64];
    float a3 = 0.f;
    #pragma unroll
    for (int k = 0; k < 32; k++){
      float h = fmaxf(fmaf(r1s[k], scd, pb + QC[k*64+d]), 0.f);
      a3 += h; acc2[k] += h;
      hrow[k*64] = (unsigned short)f2bfu(h);
    }
    ws[O_S3S + (bid*32+j)*64+d] = a3;
  }
  #pragma unroll
  for (int k = 0; k < 32; k++) s2p[(w*32+k)*64+d] = acc2[k];
  __syncthreads();
  for (int idx = t; idx < 2048; idx += 256){
    int k = idx >> 6, dd = idx & 63;
    ws[O_S2S + (bid*32+k)*64+dd] = s2p[k*64+dd] + s2p[2048+k*64+dd] + s2p[4096+k*64+dd] + s2p[6144+k*64+dd];
  }
}

// ================= S1S = sum_i h1 (register-staged loads); then P2T, Q2, R2 =================
__global__ __launch_bounds__(512) void k_hredp2(const float* __restrict__ W2, float* __restrict__ ws,
                                                const unsigned short* __restrict__ H1,
                                                unsigned short* __restrict__ P2T){
  int bid = blockIdx.x; int b = bid >> 5, j = bid & 31;
  int t = threadIdx.x;
  __shared__ float s1[2048], s1b[2048], s2[2048], s3[2048];
  int tt = t & 255, half = t >> 8;
  u32x4v vb[16];
  #pragma unroll
  for (int ii = 0; ii < 16; ii++){
    int i = half*16 + ii;
    vb[ii] = *reinterpret_cast<const u32x4v*>(H1 + (((size_t)(b*32+i)*32+j)*32)*64 + tt*8);
  }
  float acc[8];
  #pragma unroll
  for (int e = 0; e < 8; e++) acc[e] = 0.f;
  #pragma unroll
  for (int ii = 0; ii < 16; ii++){
    u16x8 v = __builtin_bit_cast(u16x8, vb[ii]);
    #pragma unroll
    for (int e = 0; e < 8; e++) acc[e] += bf2f(v[e]);
  }
  float* dsth = half ? s1b : s1;
  #pragma unroll
  for (int e = 0; e < 8; e++) dsth[tt*8+e] = acc[e];
  {
    int idx = t;
    *(f32x4*)&s2[idx*4] = *(const f32x4*)&ws[O_S2S + bid*2048 + idx*4];
    *(f32x4*)&s3[idx*4] = *(const f32x4*)&ws[O_S3S + bid*2048 + idx*4];
  }
  __syncthreads();
  for (int idx = t; idx < 2048; idx += 512){
    float v = s1[idx] + s1b[idx];
    s1[idx] = v;
    ws[O_S1S + (size_t)bid*2048 + idx] = v;
  }
  __syncthreads();
  int d = t & 63; int g = t >> 6;
  float pv[4] = {0,0,0,0}, qv[4] = {0,0,0,0}, rv[4] = {0,0,0,0};
  for (int c = 0; c < 64; c++){
    float wp = W2[(64 +c)*64 + d];
    float wq = W2[(128+c)*64 + d];
    float wr = W2[(192+c)*64 + d];
    #pragma unroll
    for (int rr = 0; rr < 4; rr++){
      int row = g*4 + rr;
      pv[rr] = fmaf(s1[row*64+c], wp, pv[rr]);
      qv[rr] = fmaf(s2[row*64+c], wq, qv[rr]);
      rv[rr] = fmaf(s3[row*64+c], wr, rv[rr]);
    }
  }
  #pragma unroll
  for (int rr = 0; rr < 4; rr++){
    int row = g*4 + rr;   // k index
    P2T[(size_t)bid*2048 + d*32 + row] = (unsigned short)f2bfu(pv[rr] * (1.f/32.f));
    ws[O_Q2 + (bid*32+row)*64 + d] = qv[rr] * (1.f/32.f);
    ws[O_R2 + (bid*32+row)*64 + d] = rv[rr] * (1.f/32.f);
  }
}

// ================= order-1 means of h1 (+ S123 accumulation) =================
__global__ __launch_bounds__(64) void k_sred(float* __restrict__ ws){
  int bid = blockIdx.x; int b = bid >> 5, m = bid & 31; int d = threadIdx.x;
  float s23 = 0.f, s13 = 0.f, s12 = 0.f;
  for (int k = 0; k < 32; k++){
    s23 += ws[O_S2S + (bid*32+k)*64+d];
    s13 += ws[O_S1S + (bid*32+k)*64+d];
  }
  for (int j = 0; j < 32; j++) s12 += ws[O_S1S + ((b*32+j)*32+m)*64+d];
  ws[O_S23H + bid*64+d] = s23 * (1.f/1024.f);
  ws[O_S13H + bid*64+d] = s13 * (1.f/1024.f);
  ws[O_S12H + bid*64+d] = s12 * (1.f/1024.f);
  atomicAdd(&ws[O_S123 + b*64+d], s23 * (1.f/32768.f));
}

// ================= A2/B2/C2 (D2 inline from S123) =================
__global__ __launch_bounds__(64) void k_ss2(const float* __restrict__ W2, float* __restrict__ ws){
  int bid = blockIdx.x; int b = bid >> 5; int t = threadIdx.x;
  __shared__ float r23[64], r13[64], r12[64], s123l[64];
  r23[t] = ws[O_S23H + bid*64+t];
  r13[t] = ws[O_S13H + bid*64+t];
  r12[t] = ws[O_S12H + bid*64+t];
  s123l[t] = ws[O_S123 + b*64+t];
  __syncthreads();
  float a = 0.f, bv = 0.f, cv = 0.f;
  for (int c = 0; c < 64; c++){
    a  += r23[c] * W2[(256 + c)*64 + t] + s123l[c] * W2[(448 + c)*64 + t];
    bv += r13[c] * W2[(320 + c)*64 + t];
    cv += r12[c] * W2[(384 + c)*64 + t];
  }
  ws[O_A2 + bid*64+t] = a; ws[O_B2 + bid*64+t] = bv; ws[O_C2 + bid*64+t] = cv;
}

// ================= heavy pass: y2 f32 -> BN2 partials + bf16 store in place =================
__global__ __launch_bounds__(256) void k_g(float* __restrict__ ws, unsigned short* __restrict__ H1,
                                           const unsigned short* __restrict__ P2T){
  int blk = blockIdx.x;
  int bid = blk >> 2; int b = bid >> 5; int jh = blk & 3;
  int t = threadIdx.x; int w = t >> 6, lane = t & 63;
  int mt = w & 1, jp = w >> 1;
  int d15 = lane & 15, kq = lane >> 4;
  __shared__ float RB2s[512];
  __shared__ float redA[256], redB[256];
  for (int idx = t; idx < 512; idx += 256){
    int jj = idx >> 6, dd = idx & 63; int j = jh*8 + jj;
    RB2s[idx] = ws[O_R2 + (bid*32+j)*64+dd] + ws[O_B2 + (b*32+j)*64+dd] + ws[O_A2 + bid*64+dd];
  }
  const unsigned short* W2bt = (const unsigned short*)(ws + O_W2BT);
  bfv8 bw[4][2];
  #pragma unroll
  for (int nt = 0; nt < 4; nt++){
    #pragma unroll
    for (int ks = 0; ks < 2; ks++){
      bw[nt][ks] = ld_bf8(W2bt + (nt*16 + d15)*64 + ks*32 + kq*8);
    }
  }
  float qc2r[4][4];
  #pragma unroll
  for (int nt = 0; nt < 4; nt++){
    int dcol = nt*16 + d15;
    #pragma unroll
    for (int r = 0; r < 4; r++){
      int kl = mt*16 + kq*4 + r;
      qc2r[nt][r] = ws[O_Q2 + (bid*32+kl)*64 + dcol] + ws[O_C2 + (b*32+kl)*64 + dcol];
    }
  }
  float ssumv[4] = {0.f,0.f,0.f,0.f}, ssqv[4] = {0.f,0.f,0.f,0.f};
  __syncthreads();
  int aoff = (mt*16 + d15)*64 + kq*8;
  unsigned short* hbase = H1 + (size_t)bid*65536 + (size_t)jh*16384;
  bfv8 a0 = ld_bf8(hbase + jp*2048 + aoff);
  bfv8 a1 = ld_bf8(hbase + jp*2048 + aoff + 32);
  u16x4 p2cur[4];
  {
    const unsigned short* pb0 = P2T + (size_t)(b*32 + jh*8 + jp)*2048 + mt*16 + kq*4;
    #pragma unroll
    for (int nt = 0; nt < 4; nt++)
      p2cur[nt] = *reinterpret_cast<const u16x4*>(pb0 + (nt*16 + d15)*32);
  }
  #pragma unroll
  for (int s = 0; s < 4; s++){
    int jj = jp + 2*s;
    bfv8 n0 = a0, n1 = a1;
    u16x4 p2nxt[4];
    if (s < 3){
      n0 = ld_bf8(hbase + (jj+2)*2048 + aoff);
      n1 = ld_bf8(hbase + (jj+2)*2048 + aoff + 32);
      const unsigned short* pbn = P2T + (size_t)(b*32 + jh*8 + jj + 2)*2048 + mt*16 + kq*4;
      #pragma unroll
      for (int nt = 0; nt < 4; nt++)
        p2nxt[nt] = *reinterpret_cast<const u16x4*>(pbn + (nt*16 + d15)*32);
    }
    #pragma unroll
    for (int nt = 0; nt < 4; nt++){
      f32x4 acc = {0.f,0.f,0.f,0.f};
      acc = __builtin_amdgcn_mfma_f32_16x16x32_bf16(a0, bw[nt][0], acc, 0, 0, 0);
      acc = __builtin_amdgcn_mfma_f32_16x16x32_bf16(a1, bw[nt][1], acc, 0, 0, 0);
      int dcol = nt*16 + d15;
      float rb = RB2s[jj*64 + dcol];
      #pragma unroll
      for (int r = 0; r < 4; r++){
        int kl = mt*16 + kq*4 + r;   // C/D: col=lane&15, row=kq*4+r
        float val = acc[r] + rb + qc2r[nt][r] + bf2f(p2cur[nt][r]);
        ssumv[nt] += val; ssqv[nt] = fmaf(val, val, ssqv[nt]);
        hbase[jj*2048 + kl*64 + dcol] = (unsigned short)f2bfu(val);
      }
    }
    a0 = n0; a1 = n1;
    if (s < 3){
      #pragma unroll
      for (int nt = 0; nt < 4; nt++) p2cur[nt] = p2nxt[nt];
    }
  }
  #pragma unroll
  for (int nt = 0; nt < 4; nt++){
    float v = ssumv[nt]; v += __shfl_xor(v,16); v += __shfl_xor(v,32);
    float q = ssqv[nt];  q += __shfl_xor(q,16); q += __shfl_xor(q,32);
    if (lane < 16){ redA[(w*4+nt)*16 + lane] = v; redB[(w*4+nt)*16 + lane] = q; }
  }
  __syncthreads();
  if (t < 128){
    int half = t >> 6, ch = t & 63;
    int nt = ch >> 4, dd15 = ch & 15;
    const float* red = half ? redB : redA;
    float acc = 0.f;
    #pragma unroll
    for (int w2 = 0; w2 < 4; w2++) acc += red[(w2*4+nt)*16 + dd15];
    ws[O_S1S + (size_t)blk*128 + t] = acc;   // coalesced 512B per-block partial
  }
}

// ================= merge BN2 partials -> SUM2/SSQ2 =================
__global__ __launch_bounds__(128) void k_bn2red(float* __restrict__ ws){
  int p = blockIdx.x; int t = threadIdx.x;
  const float* base = ws + O_S1S + (size_t)p*256*128 + t;
  float a0=0.f,a1=0.f,a2=0.f,a3=0.f;
  for (int i = 0; i < 256; i += 4){
    a0 += base[(i+0)*128]; a1 += base[(i+1)*128];
    a2 += base[(i+2)*128]; a3 += base[(i+3)*128];
  }
  atomicAdd(&ws[O_SUM2 + t], (a0+a1)+(a2+a3));   // SUM2(0..63) | SSQ2(64..127) contiguous
}

// ================= stream y2-bf16 twice: register-local partial reductions =================
__global__ __launch_bounds__(256) void k_h2red(const float* __restrict__ g2, const float* __restrict__ b2,
                                               float* __restrict__ ws, const unsigned short* __restrict__ Y2){
  int blk = blockIdx.x; int phase = blk >> 9; int bid = blk & 511;
  int t = threadIdx.x; int row = t >> 3, g = t & 7, d0 = g*8;
  float sc[8], sh[8];
  #pragma unroll
  for (int e = 0; e < 8; e++){
    int d = d0+e;
    float mu = ws[O_SUM2+d]*(1.f/524288.f);
    float var = ws[O_SSQ2+d]*(1.f/524288.f) - mu*mu;
    float s = rsqrtf(var + 1e-5f) * g2[d];
    sc[e] = s; sh[e] = b2[d] - mu*s;
  }
  float acc[8] = {0,0,0,0,0,0,0,0};
  const unsigned short* base = Y2 + (size_t)bid*65536;
  if (phase == 0){
    const unsigned short* p = base + row*64 + d0;       // + j*2048
    for (int j = 0; j < 32; j++){
      u16x8 v = *reinterpret_cast<const u16x8*>(p + j*2048);
      #pragma unroll
      for (int e = 0; e < 8; e++) acc[e] += fmaxf(fmaf(bf2f(v[e]), sc[e], sh[e]), 0.f);
    }
    float* o = ws + O_S2S + (size_t)(bid*32+row)*64 + d0;
    *(f32x4*)o = *(f32x4*)&acc[0]; *(f32x4*)(o+4) = *(f32x4*)&acc[4];
  } else {
    const unsigned short* p = base + row*2048 + d0;     // + k*64
    for (int k = 0; k < 32; k++){
      u16x8 v = *reinterpret_cast<const u16x8*>(p + k*64);
      #pragma unroll
      for (int e = 0; e < 8; e++) acc[e] += fmaxf(fmaf(bf2f(v[e]), sc[e], sh[e]), 0.f);
    }
    float* o = ws + O_S3S + (size_t)(bid*32+row)*64 + d0;
    *(f32x4*)o = *(f32x4*)&acc[0]; *(f32x4*)(o+4) = *(f32x4*)&acc[4];
  }
}

// ================= fold partials: T12 = sum_i P12, T13 = sum_i P13, T23 = sum_k P12 =================
__global__ __launch_bounds__(64) void k_tred(float* __restrict__ ws){
  int bid = blockIdx.x; int b = bid >> 5, m = bid & 31; int d = threadIdx.x;
  float t12 = 0.f, t13 = 0.f, t23 = 0.f;
  for (int u = 0; u < 32; u++){
    t12 += ws[O_S2S + ((b*32+u)*32+m)*64 + d];
    t13 += ws[O_S3S + ((b*32+u)*32+m)*64 + d];
    t23 += ws[O_S2S + ((b*32+m)*32+u)*64 + d];
  }
  ws[O_T12 + bid*64+d] = t12;
  ws[O_T13 + bid*64+d] = t13;
  ws[O_T23 + bid*64+d] = t23;
}

// ================= final head (D3 inline) =================
__global__ __launch_bounds__(64) void k_final_out1(const float* __restrict__ Wc, float* __restrict__ ws){
  int bid = blockIdx.x; int b = bid >> 5; int t = threadIdx.x;
  __shared__ float r23[64], r13[64], r12[64], l[64];
  float a = 0.f;
  for (int m = 0; m < 32; m++) a += ws[O_T23 + (b*32+m)*64 + t];
  l[t] = a * (1.f/32768.f);
  r23[t] = ws[O_T23 + bid*64+t] * (1.f/1024.f);
  r13[t] = ws[O_T13 + bid*64+t] * (1.f/1024.f);
  r12[t] = ws[O_T12 + bid*64+t] * (1.f/1024.f);
  __syncthreads();
  float o = 0.f;
  for (int c = 0; c < 64; c++){
    o += r23[c]*Wc[c*64+t] + r13[c]*Wc[(64+c)*64+t] + r12[c]*Wc[(128+c)*64+t] + l[c]*Wc[(192+c)*64+t];
  }
  ws[O_OUT1 + bid*64+t] = o;
  atomicAdd(&ws[O_SUMC + t], o);
  atomicAdd(&ws[O_SSQC + t], o*o);
}

__global__ __launch_bounds__(64) void k_final_bn(const float* __restrict__ gc, const float* __restrict__ bc,
                                                 const float* __restrict__ ws, float* __restrict__ out){
  int bid = blockIdx.x; int t = threadIdx.x;
  float mu = ws[O_SUMC+t] * (1.f/512.f);
  float var = ws[O_SSQC+t] * (1.f/512.f) - mu*mu;
  float rs = rsqrtf(var + 1e-5f);
  out[bid*64 + t] = (ws[O_OUT1 + bid*64+t] - mu) * rs * gc[t] + bc[t];
}

extern "C" void kernel_launch(void* const* d_in, const int* in_sizes, int n_in,
                              void* d_out, int out_size, void* d_ws, size_t ws_size,
                              hipStream_t stream) {
  const float* x   = (const float*)d_in[0];
  const float* xn  = (const float*)d_in[1];
  const float* W1  = (const float*)d_in[2];
  const float* Wn1 = (const float*)d_in[3];
  const float* g1  = (const float*)d_in[4];
  const float* b1  = (const float*)d_in[5];
  const float* W2  = (const float*)d_in[6];
  const float* g2  = (const float*)d_in[7];
  const float* b2p = (const float*)d_in[8];
  const float* Wc  = (const float*)d_in[9];
  const float* gc  = (const float*)d_in[10];
  const float* bc  = (const float*)d_in[11];
  float* out = (float*)d_out;
  float* ws  = (float*)d_ws;
  unsigned short* H1  = (unsigned short*)(ws + O_H1);
  unsigned short* P2T = (unsigned short*)(ws + O_P2T);
  (void)in_sizes; (void)n_in; (void)out_size; (void)ws_size;

  k_setup   <<<35,    512, 0, stream>>>(x, W1, W2, ws);   // + zero-accum blocks
  k_pairs1s <<<1536,  64,  0, stream>>>(x, xn, Wn1, ws);
  k_bn1a    <<<128,   256, 0, stream>>>(ws);
  k_bn1bfin <<<1,     64,  0, stream>>>(g1, b1, ws);
  k_sweep1  <<<512,   256, 0, stream>>>(ws, H1);
  k_hredp2  <<<512,   512, 0, stream>>>(W2, ws, H1, P2T);
  k_sred    <<<512,   64,  0, stream>>>(ws);
  k_ss2     <<<512,   64,  0, stream>>>(W2, ws);
  k_g       <<<2048,  256, 0, stream>>>(ws, H1, P2T);   // y2 + bf16 in-place + BN2 partials
  k_bn2red  <<<8,     128, 0, stream>>>(ws);
  k_h2red   <<<1024,  256, 0, stream>>>(g2, b2p, ws, H1);
  k_tred    <<<512,   64,  0, stream>>>(ws);
  k_final_out1<<<512, 64,  0, stream>>>(Wc, ws);
  k_final_bn<<<512,   64,  0, stream>>>(gc, bc, ws, out);
}